// Round 3
// baseline (58.099 us; speedup 1.0000x reference)
//
#include <hip/hip_runtime.h>

// Problem constants (from reference): B=64, S=512, D=1024, fp32 in/out.
#define BS 64
#define SS 512
#define DD 1024
#define WPB 8          // output positions (words) per block
#define NVEC (DD / 4)  // 256 float4 per row

typedef float f4 __attribute__((ext_vector_type(4)));

__global__ __launch_bounds__(256) void merge_subword_kernel(
    const float* __restrict__ h,     // [B, S, D]
    const int*   __restrict__ wid,   // [B, S] sorted, contiguous word ids
    float*       __restrict__ out)   // [B, S, D]
{
    const int chunk = blockIdx.x;    // which group of WPB output positions
    const int b     = blockIdx.y;    // batch row
    const int w0    = chunk * WPB;

    __shared__ int s_wid[SS];
    __shared__ int s_lo[WPB], s_hi[WPB];

    // Stage the word_ids row in LDS (2 KB), coalesced.
    const int* row = wid + b * SS;
    for (int i = threadIdx.x; i < SS; i += 256) s_wid[i] = row[i];
    __syncthreads();

    // WPB threads each binary-search their own output position in LDS.
    if (threadIdx.x < WPB) {
        const int w = w0 + (int)threadIdx.x;
        // lower_bound(w): first t with s_wid[t] >= w
        int lo = 0, hi = SS;
        while (lo < hi) { int m = (lo + hi) >> 1; if (s_wid[m] < w) lo = m + 1; else hi = m; }
        s_lo[threadIdx.x] = lo;
        // upper_bound(w): first t with s_wid[t] > w
        int lo2 = lo, hi2 = SS;
        while (lo2 < hi2) { int m = (lo2 + hi2) >> 1; if (s_wid[m] <= w) lo2 = m + 1; else hi2 = m; }
        s_hi[threadIdx.x] = lo2;
    }
    __syncthreads();

    const int tot = s_wid[SS - 1] + 1;   // sorted -> last element is the max
    const int tid = threadIdx.x;         // 256 threads x float4 = 1024 = D

    #pragma unroll
    for (int k = 0; k < WPB; ++k) {
        const int w = w0 + k;
        f4* dst = (f4*)(out + ((size_t)b * SS + w) * DD);
        if (w >= tot) {
            // passthrough: keep original values
            const f4* src = (const f4*)(h + ((size_t)b * SS + w) * DD);
            __builtin_nontemporal_store(src[tid], dst + tid);
        } else {
            const int lo = s_lo[k], hi = s_hi[k];
            const float inv = 1.0f / (float)(hi - lo);
            f4 acc = (f4)(0.f);
            const f4* base = (const f4*)(h + ((size_t)b * SS + lo) * DD);
            for (int t = 0; t < hi - lo; ++t) {
                acc += base[(size_t)t * NVEC + tid];
            }
            acc *= inv;
            __builtin_nontemporal_store(acc, dst + tid);
        }
    }
}

extern "C" void kernel_launch(void* const* d_in, const int* in_sizes, int n_in,
                              void* d_out, int out_size, void* d_ws, size_t ws_size,
                              hipStream_t stream) {
    (void)in_sizes; (void)n_in; (void)out_size; (void)d_ws; (void)ws_size;
    const float* h   = (const float*)d_in[0];
    const int*   wid = (const int*)d_in[1];
    float*       out = (float*)d_out;

    dim3 grid(SS / WPB, BS);   // 64 x 64 blocks, each covers 8 output rows
    dim3 block(256);
    merge_subword_kernel<<<grid, block, 0, stream>>>(h, wid, out);
}

// Round 4
// 56.538 us; speedup vs baseline: 1.0276x; 1.0276x over previous
//
#include <hip/hip_runtime.h>

// Problem constants (from reference): B=64, S=512, D=1024, fp32 in/out.
#define BS 64
#define SS 512
#define DD 1024
#define NVEC (DD / 4)  // 256 float4 per row

typedef float f4 __attribute__((ext_vector_type(4)));

// Kernel A: per batch row, compute packed segment bounds.
// bounds[b*SS + w] = lo | (len << 16) for w < tot, 0xFFFFFFFF for w >= tot.
__global__ __launch_bounds__(512) void bounds_kernel(
    const int* __restrict__ wid,        // [B, S] sorted, contiguous word ids
    unsigned int* __restrict__ bounds)  // [B, S]
{
    const int b = blockIdx.x;
    const int t = threadIdx.x;          // 512 threads = S
    const int* row = wid + b * SS;

    __shared__ int s_lo[SS + 1];
    __shared__ int s_tot;

    const int w_t  = row[t];
    const int prev = (t == 0) ? -1 : row[t - 1];
    if (t == SS - 1) { s_tot = w_t + 1; s_lo[w_t + 1] = SS; }
    if (w_t != prev) s_lo[w_t] = t;     // segment start
    __syncthreads();

    const int tot = s_tot;
    unsigned int val;
    if (t < tot) {
        const int lo  = s_lo[t];
        const int len = s_lo[t + 1] - lo;
        val = (unsigned int)lo | ((unsigned int)len << 16);
    } else {
        val = 0xFFFFFFFFu;              // passthrough sentinel
    }
    bounds[b * SS + t] = val;
}

// Kernel B: one block per output row (b, w). Uniform scalar load of bounds,
// then fully coalesced float4 stream. No LDS, no syncthreads.
__global__ __launch_bounds__(256) void merge_subword_kernel(
    const float* __restrict__ h,              // [B, S, D]
    const unsigned int* __restrict__ bounds,  // [B, S] packed lo|len<<16
    float* __restrict__ out)                  // [B, S, D]
{
    const int w = blockIdx.x;
    const int b = blockIdx.y;
    const unsigned int bd = bounds[b * SS + w];   // block-uniform -> s_load
    const int tid = threadIdx.x;                  // 256 x float4 = 1024 = D

    f4* dst = (f4*)(out + ((size_t)b * SS + w) * DD);

    if (bd == 0xFFFFFFFFu) {
        // passthrough: keep original values
        const f4* src = (const f4*)(h + ((size_t)b * SS + w) * DD);
        __builtin_nontemporal_store(src[tid], dst + tid);
    } else {
        const int lo  = (int)(bd & 0xFFFFu);
        const int len = (int)(bd >> 16);
        const float inv = 1.0f / (float)len;
        f4 acc = (f4)(0.f);
        const f4* base = (const f4*)(h + ((size_t)b * SS + lo) * DD);
        for (int t = 0; t < len; ++t) {
            acc += base[(size_t)t * NVEC + tid];
        }
        acc *= inv;
        __builtin_nontemporal_store(acc, dst + tid);
    }
}

extern "C" void kernel_launch(void* const* d_in, const int* in_sizes, int n_in,
                              void* d_out, int out_size, void* d_ws, size_t ws_size,
                              hipStream_t stream) {
    (void)in_sizes; (void)n_in; (void)out_size; (void)ws_size;
    const float* h   = (const float*)d_in[0];
    const int*   wid = (const int*)d_in[1];
    float*       out = (float*)d_out;
    unsigned int* bounds = (unsigned int*)d_ws;   // needs B*S*4 = 128 KB

    bounds_kernel<<<dim3(BS), dim3(SS), 0, stream>>>(wid, bounds);
    merge_subword_kernel<<<dim3(SS, BS), dim3(256), 0, stream>>>(h, bounds, out);
}